// Round 9
// baseline (184.154 us; speedup 1.0000x reference)
//
#include <hip/hip_runtime.h>

#define NB 256
#define NA 64
#define NG 978
#define CELL_IN 978
#define DOSE_IN 12
#define GLOBAL_F 306
#define EXP_IN 434
#define NE 4

// ---- workspace layout (float offsets) ----
#define WS_SEL 0                      // [256][4] : e1, e2, gate1, gate2
#define WS_U   (WS_SEL + NB*4)        // [256][2][128] u for the 2 active experts
#define WS_V   (WS_U + NB*256)        // [978][512]  v[g][e*128+h]
// total ~567k floats ~2.3 MB

#define AB_GRID (NB + 245)            // 256 b-blocks + 245 a-blocks (4 genes each)

__device__ __forceinline__ float wave_reduce(float p) {
    #pragma unroll
    for (int off = 32; off > 0; off >>= 1) p += __shfl_down(p, off, 64);
    return p;
}

// ---------------------------------------------------------------------------
// AB: blocks [0,256): full per-batch pipeline (drug/dose/cell/gate/top2/u).
//     blocks [256,501): v[g,e,h] = gene[g,:] @ eW1[e,306:,:]  (4 genes/block)
// (unchanged from round 8 — A/B isolation of the new epilogue)
// ---------------------------------------------------------------------------
__global__ __launch_bounds__(1024) void ab_kernel(
    const float* __restrict__ drug, const float* __restrict__ gex,
    const float* __restrict__ idose,
    const float* __restrict__ cW1, const float* __restrict__ cb1,
    const float* __restrict__ cW2, const float* __restrict__ cb2,
    const float* __restrict__ cW3, const float* __restrict__ cb3,
    const float* __restrict__ dW1, const float* __restrict__ db1,
    const float* __restrict__ dW2, const float* __restrict__ db2,
    const float* __restrict__ gW1, const float* __restrict__ gb1,
    const float* __restrict__ gW2, const float* __restrict__ gb2,
    const float* __restrict__ eW1, const float* __restrict__ eb1,
    const float* __restrict__ gene,
    float* __restrict__ ws, float* __restrict__ cell_out)
{
    __shared__ float s_gex[CELL_IN];
    __shared__ float s_g[GLOBAL_F];
    __shared__ float s_h1[200];
    __shared__ float s_h2[100];
    __shared__ float s_gh[128];
    __shared__ float s_d1[64];
    __shared__ int   s_isel[2];
    __shared__ float s_part[16 * 200];
    __shared__ float s_pu[32 * 128];
    __shared__ float s_ag[4][128];
    __shared__ float s_ap[4][8][128];

    const int blk = blockIdx.x, tid = threadIdx.x;

    if (blk >= NB) {
        // ================= a-part: v GEMM, 4 genes per block ===============
        const int gq = tid >> 8, lt = tid & 255;
        const int g = (blk - NB) * 4 + gq;
        if (lt < 128) s_ag[gq][lt] = (g < NG) ? gene[g * 128 + lt] : 0.f;
        __syncthreads();
        const int e = lt >> 6, ks = (lt >> 5) & 1, h4 = lt & 31;
        const float* wp = eW1 + ((size_t)e * EXP_IN + GLOBAL_F) * 128 + 4 * h4;
        float4 acc = {0.f, 0.f, 0.f, 0.f};
        const int k0 = ks * 64;
        #pragma unroll 8
        for (int k = k0; k < k0 + 64; ++k) {
            float4 w = *(const float4*)(wp + (size_t)k * 128);
            float x = s_ag[gq][k];
            acc.x += x * w.x; acc.y += x * w.y; acc.z += x * w.z; acc.w += x * w.w;
        }
        *(float4*)(&s_ap[gq][e * 2 + ks][4 * h4]) = acc;
        __syncthreads();
        if (lt < 128 && g < NG) {
            int oe = lt >> 5, oh4 = lt & 31;
            float4 p0 = *(const float4*)(&s_ap[gq][oe * 2 + 0][4 * oh4]);
            float4 p1 = *(const float4*)(&s_ap[gq][oe * 2 + 1][4 * oh4]);
            float4 o = {p0.x + p1.x, p0.y + p1.y, p0.z + p1.z, p0.w + p1.w};
            *(float4*)(ws + WS_V + (size_t)g * 512 + oe * 128 + 4 * oh4) = o;
        }
        return;
    }

    // ==================== b-part: per-batch pipeline =======================
    const int b = blk;

    // ---- P0: stage gex; drug partials; dose layer1 ----
    if (tid < CELL_IN) s_gex[tid] = gex[b * CELL_IN + tid];
    {
        int row = tid >> 7, d = tid & 127;
        const float* p = drug + ((size_t)b * NA) * 128 + d;
        float acc = 0.f;
        #pragma unroll
        for (int i = 0; i < 8; ++i) acc += p[(size_t)(i * 8 + row) * 128];
        s_pu[row * 128 + d] = acc;
    }
    __syncthreads();
    if (tid < 128) {
        float a = 0.f;
        #pragma unroll
        for (int r = 0; r < 8; ++r) a += s_pu[r * 128 + tid];
        s_g[tid] = a;
    } else if (tid < 192) {
        int j = tid - 128;
        float acc = db1[j];
        #pragma unroll
        for (int i = 0; i < DOSE_IN; ++i)
            acc += idose[b * DOSE_IN + i] * dW1[i * 64 + j];
        s_d1[j] = fmaxf(acc, 0.f);
    }
    __syncthreads();
    if (tid < 128) {
        float acc = db2[tid];
        #pragma unroll 8
        for (int i = 0; i < 64; ++i) acc += s_d1[i] * dW2[i * 128 + tid];
        s_g[178 + tid] = fmaxf(acc, 0.f);
    }
    __syncthreads();

    // ---- P1: cell1 978->200, 16-way K-split, float4 ----
    {
        int q = tid & 63, ks = tid >> 6;
        if (q < 50) {
            int i0 = ks * 62, i1 = min(i0 + 62, CELL_IN);
            float4 acc = {0.f, 0.f, 0.f, 0.f};
            #pragma unroll 4
            for (int i = i0; i < i1; ++i) {
                float4 w = *(const float4*)(cW1 + (size_t)i * 200 + 4 * q);
                float x = s_gex[i];
                acc.x += x * w.x; acc.y += x * w.y; acc.z += x * w.z; acc.w += x * w.w;
            }
            *(float4*)(&s_part[ks * 200 + 4 * q]) = acc;
        }
    }
    __syncthreads();
    if (tid < 200) {
        float a = cb1[tid];
        #pragma unroll
        for (int ks = 0; ks < 16; ++ks) a += s_part[ks * 200 + tid];
        s_h1[tid] = fmaxf(a, 0.f);
    }
    __syncthreads();

    // ---- P2: cell2 200->100, 16-way K-split, float4 ----
    {
        int q = tid & 31, ks = tid >> 5;
        if (q < 25 && ks < 16) {
            int i0 = ks * 13, i1 = min(i0 + 13, 200);
            float4 acc = {0.f, 0.f, 0.f, 0.f};
            #pragma unroll
            for (int i = i0; i < i1; ++i) {
                float4 w = *(const float4*)(cW2 + (size_t)i * 100 + 4 * q);
                float x = s_h1[i];
                acc.x += x * w.x; acc.y += x * w.y; acc.z += x * w.z; acc.w += x * w.w;
            }
            *(float4*)(&s_part[ks * 100 + 4 * q]) = acc;
        }
    }
    __syncthreads();
    if (tid < 100) {
        float a = cb2[tid];
        #pragma unroll
        for (int ks = 0; ks < 16; ++ks) a += s_part[ks * 100 + tid];
        s_h2[tid] = fmaxf(a, 0.f);
    }
    __syncthreads();

    // ---- P3: cell3 100->50, 8-way K-split ----
    {
        int j = tid & 63, ks = tid >> 6;
        if (j < 50 && ks < 8) {
            int i0 = ks * 13, i1 = min(i0 + 13, 100);
            float acc = 0.f;
            #pragma unroll
            for (int i = i0; i < i1; ++i) acc += s_h2[i] * cW3[i * 50 + j];
            s_part[ks * 64 + j] = acc;
        }
    }
    __syncthreads();
    if (tid < 50) {
        float a = cb3[tid];
        #pragma unroll
        for (int ks = 0; ks < 8; ++ks) a += s_part[ks * 64 + tid];
        float r = fmaxf(a, 0.f);
        s_g[128 + tid] = r;
        cell_out[b * 50 + tid] = r;
    }
    __syncthreads();

    // ---- P4: gate1 306->128, 16-way K-split, float4 ----
    {
        int q = tid & 31, ks = tid >> 5;
        if (ks < 16) {
            int i0 = ks * 20, i1 = min(i0 + 20, GLOBAL_F);
            float4 acc = {0.f, 0.f, 0.f, 0.f};
            #pragma unroll
            for (int i = i0; i < i1; ++i) {
                float4 w = *(const float4*)(gW1 + (size_t)i * 128 + 4 * q);
                float x = s_g[i];
                acc.x += x * w.x; acc.y += x * w.y; acc.z += x * w.z; acc.w += x * w.w;
            }
            *(float4*)(&s_part[ks * 128 + 4 * q]) = acc;
        }
    }
    __syncthreads();
    if (tid < 128) {
        float a = gb1[tid];
        #pragma unroll
        for (int ks = 0; ks < 16; ++ks) a += s_part[ks * 128 + tid];
        s_gh[tid] = fmaxf(a, 0.f);
    }
    __syncthreads();

    // ---- P5: logits + top-2 softmax -> s_isel, ws sel ----
    if (tid < 64) {
        float h0 = s_gh[tid], h1 = s_gh[tid + 64];
        float logit[NE];
        #pragma unroll
        for (int j = 0; j < NE; ++j) {
            float p = h0 * gW2[tid * NE + j] + h1 * gW2[(tid + 64) * NE + j];
            p = wave_reduce(p);
            logit[j] = p + gb2[j];
        }
        if (tid == 0) {
            int i1 = 0; float v1 = logit[0];
            #pragma unroll
            for (int i = 1; i < NE; ++i) if (logit[i] > v1) { v1 = logit[i]; i1 = i; }
            int i2 = -1; float v2 = -__builtin_inff();
            #pragma unroll
            for (int i = 0; i < NE; ++i) {
                if (i == i1) continue;
                if (logit[i] > v2) { v2 = logit[i]; i2 = i; }
            }
            float ex = __expf(v2 - v1);
            float inv = 1.f / (1.f + ex);
            s_isel[0] = i1; s_isel[1] = i2;
            ws[WS_SEL + b * 4 + 0] = (float)i1;
            ws[WS_SEL + b * 4 + 1] = (float)i2;
            ws[WS_SEL + b * 4 + 2] = inv;
            ws[WS_SEL + b * 4 + 3] = ex * inv;
        }
    }
    __syncthreads();

    // ---- P6: u for the 2 ACTIVE experts, 16-way K-split, float4 ----
    {
        int es = tid >> 9, ks = (tid >> 5) & 15, h4 = tid & 31;
        int e = s_isel[es];
        int i0 = ks * 20, i1 = min(i0 + 20, GLOBAL_F);
        const float* wp = eW1 + (size_t)e * EXP_IN * 128 + 4 * h4;
        float4 acc = {0.f, 0.f, 0.f, 0.f};
        #pragma unroll
        for (int i = i0; i < i1; ++i) {
            float4 w = *(const float4*)(wp + (size_t)i * 128);
            float x = s_g[i];
            acc.x += x * w.x; acc.y += x * w.y; acc.z += x * w.z; acc.w += x * w.w;
        }
        *(float4*)(&s_pu[(es * 16 + ks) * 128 + 4 * h4]) = acc;
    }
    __syncthreads();
    if (tid < 256) {
        int es = tid >> 7, h = tid & 127;
        int e = s_isel[es];
        float a = eb1[e * 128 + h];
        #pragma unroll
        for (int ks = 0; ks < 16; ++ks) a += s_pu[(es * 16 + ks) * 128 + h];
        ws[WS_U + (size_t)b * 256 + es * 128 + h] = a;
    }
}

// ---------------------------------------------------------------------------
// C (round 9 rewrite): gene-per-lane epilogue.
// grid = 256 batches x 4 gene-quarters = 1024 blocks, 256 threads.
// u/w2/gates block-uniform (LDS broadcast, conflict-free); v read directly
// from global (per-lane sequential 512B runs, L1-absorbed); pred writes
// fully coalesced (consecutive lanes -> consecutive genes).
// ---------------------------------------------------------------------------
__global__ __launch_bounds__(256) void c_kernel(
    const float* __restrict__ eW2, const float* __restrict__ eb2,
    const float* __restrict__ ws, float* __restrict__ pred)
{
    __shared__ float s_u[256];
    __shared__ float s_w2[256];
    const int b = blockIdx.x >> 2, qt = blockIdx.x & 3, tid = threadIdx.x;

    // block-uniform selection (scalarized by compiler; L2-broadcast reads)
    const int ea = (int)ws[WS_SEL + b * 4 + 0];
    const int eb = (int)ws[WS_SEL + b * 4 + 1];
    const float gA = ws[WS_SEL + b * 4 + 2];
    const float gB = ws[WS_SEL + b * 4 + 3];
    const float bA = eb2[ea], bB = eb2[eb];

    // stage u (both active experts) and their w2 columns
    s_u[tid] = ws[WS_U + (size_t)b * 256 + tid];
    s_w2[tid] = (tid < 128) ? eW2[ea * 128 + tid] : eW2[eb * 128 + (tid - 128)];
    __syncthreads();

    const int g = qt * 256 + tid;
    if (g < NG) {
        const float4* vA = (const float4*)(ws + WS_V + (size_t)g * 512 + ea * 128);
        const float4* vB = (const float4*)(ws + WS_V + (size_t)g * 512 + eb * 128);
        float dA = 0.f, dB = 0.f;
        #pragma unroll 8
        for (int k = 0; k < 32; ++k) {
            float4 va = vA[k], vb = vB[k];
            // s_u/s_w2 indices are wave-uniform -> LDS broadcast, no conflicts
            dA += fmaxf(s_u[4*k+0] + va.x, 0.f) * s_w2[4*k+0]
                + fmaxf(s_u[4*k+1] + va.y, 0.f) * s_w2[4*k+1]
                + fmaxf(s_u[4*k+2] + va.z, 0.f) * s_w2[4*k+2]
                + fmaxf(s_u[4*k+3] + va.w, 0.f) * s_w2[4*k+3];
            dB += fmaxf(s_u[128+4*k+0] + vb.x, 0.f) * s_w2[128+4*k+0]
                + fmaxf(s_u[128+4*k+1] + vb.y, 0.f) * s_w2[128+4*k+1]
                + fmaxf(s_u[128+4*k+2] + vb.z, 0.f) * s_w2[128+4*k+2]
                + fmaxf(s_u[128+4*k+3] + vb.w, 0.f) * s_w2[128+4*k+3];
        }
        pred[(size_t)b * NG + g] = gA * (dA + bA) + gB * (dB + bB);
    }
}

// ---------------------------------------------------------------------------
extern "C" void kernel_launch(void* const* d_in, const int* in_sizes, int n_in,
                              void* d_out, int out_size, void* d_ws, size_t ws_size,
                              hipStream_t stream) {
    const float* drug  = (const float*)d_in[0];
    const float* gex   = (const float*)d_in[1];
    const float* idose = (const float*)d_in[2];
    const float* cW1 = (const float*)d_in[3];  const float* cb1 = (const float*)d_in[4];
    const float* cW2 = (const float*)d_in[5];  const float* cb2 = (const float*)d_in[6];
    const float* cW3 = (const float*)d_in[7];  const float* cb3 = (const float*)d_in[8];
    const float* dW1 = (const float*)d_in[9];  const float* db1 = (const float*)d_in[10];
    const float* dW2 = (const float*)d_in[11]; const float* db2 = (const float*)d_in[12];
    const float* gene = (const float*)d_in[13];
    const float* gW1 = (const float*)d_in[14]; const float* gb1 = (const float*)d_in[15];
    const float* gW2 = (const float*)d_in[16]; const float* gb2 = (const float*)d_in[17];
    const float* eW1 = (const float*)d_in[18]; const float* eb1 = (const float*)d_in[19];
    const float* eW2 = (const float*)d_in[20]; const float* eb2 = (const float*)d_in[21];

    float* ws   = (float*)d_ws;
    float* out  = (float*)d_out;
    float* pred = out;               // [B, G]
    float* cell = out + NB * NG;     // [B, 50]

    ab_kernel<<<AB_GRID, 1024, 0, stream>>>(drug, gex, idose,
        cW1, cb1, cW2, cb2, cW3, cb3, dW1, db1, dW2, db2,
        gW1, gb1, gW2, gb2, eW1, eb1, gene, ws, cell);
    c_kernel<<<NB * 4, 256, 0, stream>>>(eW2, eb2, ws, pred);
}

// Round 10
// 180.060 us; speedup vs baseline: 1.0227x; 1.0227x over previous
//
#include <hip/hip_runtime.h>

#define NB 256
#define NA 64
#define NG 978
#define CELL_IN 978
#define DOSE_IN 12
#define GLOBAL_F 306
#define EXP_IN 434
#define NE 4

// ---- workspace layout (float offsets) ----
// v is stored GENE-TRANSPOSED: v_t[tile][e*128+h][64]  (16 tiles of 64 genes)
#define WS_SEL 0                       // [256][4] : e1, e2, gate1, gate2
#define WS_U   (WS_SEL + NB*4)         // [256][2][128]
#define WS_V   (WS_U + NB*256)         // [16][512][64] = 524288 floats
// total ~591k floats ~2.4 MB

#define A_BLOCKS 64                    // 16 tiles x 4 experts
#define AB_GRID  (NB + A_BLOCKS)

// ---- shared-memory pool (aliased between a-part and b-part) ----
// b-part: part 3200 | pu 4096 | gex 978 | g 306 | h1 200 | h2 100 | gh 128 | d1 64  = 9072
// a-part: s_gene [64][129] = 8256  (overlays the same pool)
#define SM_PART 0
#define SM_PU   3200
#define SM_GEX  7296
#define SM_G    8274
#define SM_H1   8580
#define SM_H2   8780
#define SM_GH   8880
#define SM_D1   9008
#define SM_SIZE 9072

__device__ __forceinline__ float wave_reduce(float p) {
    #pragma unroll
    for (int off = 32; off > 0; off >>= 1) p += __shfl_down(p, off, 64);
    return p;
}

// ---------------------------------------------------------------------------
// AB: blocks [0,256): per-batch pipeline (drug/dose/cell/gate/top2/u).
//     blocks [256,320): v_t producer — one (64-gene tile, expert) per block.
// ---------------------------------------------------------------------------
__global__ __launch_bounds__(1024) void ab_kernel(
    const float* __restrict__ drug, const float* __restrict__ gex,
    const float* __restrict__ idose,
    const float* __restrict__ cW1, const float* __restrict__ cb1,
    const float* __restrict__ cW2, const float* __restrict__ cb2,
    const float* __restrict__ cW3, const float* __restrict__ cb3,
    const float* __restrict__ dW1, const float* __restrict__ db1,
    const float* __restrict__ dW2, const float* __restrict__ db2,
    const float* __restrict__ gW1, const float* __restrict__ gb1,
    const float* __restrict__ gW2, const float* __restrict__ gb2,
    const float* __restrict__ eW1, const float* __restrict__ eb1,
    const float* __restrict__ gene,
    float* __restrict__ ws, float* __restrict__ cell_out)
{
    __shared__ float smem[SM_SIZE];
    __shared__ int   s_isel[2];

    const int blk = blockIdx.x, tid = threadIdx.x;

    if (blk >= NB) {
        // ============ a-part: v_t[tile][e*128+h][g_in], coalesced ==========
        const int ablk = blk - NB;            // 0..63
        const int tile = ablk >> 2, e = ablk & 3;
        float* s_gene = smem;                 // [64][129] padded

        for (int i = tid; i < 64 * 128; i += 1024) {
            int gl = i >> 7, k = i & 127;
            int g = tile * 64 + gl;
            s_gene[gl * 129 + k] = (g < NG) ? gene[g * 128 + k] : 0.f;
        }
        __syncthreads();

        const int h16 = tid >> 6, g_in = tid & 63;   // 16 h-slices x 64 genes
        const float* wbase = eW1 + ((size_t)e * EXP_IN + GLOBAL_F) * 128 + h16 * 8;
        float acc[8] = {};
        #pragma unroll 4
        for (int k = 0; k < 128; ++k) {
            float x = s_gene[g_in * 129 + k];        // padded: conflict-free
            float4 w0 = *(const float4*)(wbase + (size_t)k * 128);
            float4 w1 = *(const float4*)(wbase + (size_t)k * 128 + 4);
            acc[0] += x * w0.x; acc[1] += x * w0.y;
            acc[2] += x * w0.z; acc[3] += x * w0.w;
            acc[4] += x * w1.x; acc[5] += x * w1.y;
            acc[6] += x * w1.z; acc[7] += x * w1.w;
        }
        float* vout = ws + WS_V + ((size_t)tile * 512 + e * 128 + h16 * 8) * 64 + g_in;
        #pragma unroll
        for (int j = 0; j < 8; ++j) vout[(size_t)j * 64] = acc[j];  // lane=gene: coalesced
        return;
    }

    // ==================== b-part: per-batch pipeline =======================
    const int b = blk;
    float* s_part = smem + SM_PART;
    float* s_pu   = smem + SM_PU;
    float* s_gex  = smem + SM_GEX;
    float* s_g    = smem + SM_G;
    float* s_h1   = smem + SM_H1;
    float* s_h2   = smem + SM_H2;
    float* s_gh   = smem + SM_GH;
    float* s_d1   = smem + SM_D1;

    // ---- P0: stage gex; drug partials; dose layer1 ----
    if (tid < CELL_IN) s_gex[tid] = gex[b * CELL_IN + tid];
    {
        int row = tid >> 7, d = tid & 127;
        const float* p = drug + ((size_t)b * NA) * 128 + d;
        float acc = 0.f;
        #pragma unroll
        for (int i = 0; i < 8; ++i) acc += p[(size_t)(i * 8 + row) * 128];
        s_pu[row * 128 + d] = acc;
    }
    __syncthreads();
    if (tid < 128) {
        float a = 0.f;
        #pragma unroll
        for (int r = 0; r < 8; ++r) a += s_pu[r * 128 + tid];
        s_g[tid] = a;
    } else if (tid < 192) {
        int j = tid - 128;
        float acc = db1[j];
        #pragma unroll
        for (int i = 0; i < DOSE_IN; ++i)
            acc += idose[b * DOSE_IN + i] * dW1[i * 64 + j];
        s_d1[j] = fmaxf(acc, 0.f);
    }
    __syncthreads();
    if (tid < 128) {
        float acc = db2[tid];
        #pragma unroll 8
        for (int i = 0; i < 64; ++i) acc += s_d1[i] * dW2[i * 128 + tid];
        s_g[178 + tid] = fmaxf(acc, 0.f);
    }
    __syncthreads();

    // ---- P1: cell1 978->200, 16-way K-split, dual interleaved float4 accs ----
    {
        int q = tid & 63, ks = tid >> 6;
        if (q < 50) {
            int i0 = ks * 62, i1 = min(i0 + 62, CELL_IN);
            int n = i1 - i0, h2 = n >> 1;
            float4 a0 = {0.f, 0.f, 0.f, 0.f}, a1 = {0.f, 0.f, 0.f, 0.f};
            #pragma unroll 4
            for (int t = 0; t < h2; ++t) {
                int ia = i0 + t, ib = i0 + h2 + t;
                float4 wa = *(const float4*)(cW1 + (size_t)ia * 200 + 4 * q);
                float4 wb = *(const float4*)(cW1 + (size_t)ib * 200 + 4 * q);
                float xa = s_gex[ia], xb = s_gex[ib];
                a0.x += xa * wa.x; a0.y += xa * wa.y; a0.z += xa * wa.z; a0.w += xa * wa.w;
                a1.x += xb * wb.x; a1.y += xb * wb.y; a1.z += xb * wb.z; a1.w += xb * wb.w;
            }
            if (n & 1) {
                int ia = i1 - 1;
                float4 wa = *(const float4*)(cW1 + (size_t)ia * 200 + 4 * q);
                float xa = s_gex[ia];
                a0.x += xa * wa.x; a0.y += xa * wa.y; a0.z += xa * wa.z; a0.w += xa * wa.w;
            }
            float4 s = {a0.x + a1.x, a0.y + a1.y, a0.z + a1.z, a0.w + a1.w};
            *(float4*)(&s_part[ks * 200 + 4 * q]) = s;
        }
    }
    __syncthreads();
    if (tid < 200) {
        float a = cb1[tid];
        #pragma unroll
        for (int ks = 0; ks < 16; ++ks) a += s_part[ks * 200 + tid];
        s_h1[tid] = fmaxf(a, 0.f);
    }
    __syncthreads();

    // ---- P2: cell2 200->100, 16-way K-split, float4 ----
    {
        int q = tid & 31, ks = tid >> 5;
        if (q < 25 && ks < 16) {
            int i0 = ks * 13, i1 = min(i0 + 13, 200);
            float4 acc = {0.f, 0.f, 0.f, 0.f};
            #pragma unroll
            for (int i = i0; i < i1; ++i) {
                float4 w = *(const float4*)(cW2 + (size_t)i * 100 + 4 * q);
                float x = s_h1[i];
                acc.x += x * w.x; acc.y += x * w.y; acc.z += x * w.z; acc.w += x * w.w;
            }
            *(float4*)(&s_part[ks * 100 + 4 * q]) = acc;
        }
    }
    __syncthreads();
    if (tid < 100) {
        float a = cb2[tid];
        #pragma unroll
        for (int ks = 0; ks < 16; ++ks) a += s_part[ks * 100 + tid];
        s_h2[tid] = fmaxf(a, 0.f);
    }
    __syncthreads();

    // ---- P3: cell3 100->50, 8-way K-split ----
    {
        int j = tid & 63, ks = tid >> 6;
        if (j < 50 && ks < 8) {
            int i0 = ks * 13, i1 = min(i0 + 13, 100);
            float acc = 0.f;
            #pragma unroll
            for (int i = i0; i < i1; ++i) acc += s_h2[i] * cW3[i * 50 + j];
            s_part[ks * 64 + j] = acc;
        }
    }
    __syncthreads();
    if (tid < 50) {
        float a = cb3[tid];
        #pragma unroll
        for (int ks = 0; ks < 8; ++ks) a += s_part[ks * 64 + tid];
        float r = fmaxf(a, 0.f);
        s_g[128 + tid] = r;
        cell_out[b * 50 + tid] = r;
    }
    __syncthreads();

    // ---- P4: gate1 306->128, 16-way K-split, float4 ----
    {
        int q = tid & 31, ks = tid >> 5;
        if (ks < 16) {
            int i0 = ks * 20, i1 = min(i0 + 20, GLOBAL_F);
            float4 acc = {0.f, 0.f, 0.f, 0.f};
            #pragma unroll
            for (int i = i0; i < i1; ++i) {
                float4 w = *(const float4*)(gW1 + (size_t)i * 128 + 4 * q);
                float x = s_g[i];
                acc.x += x * w.x; acc.y += x * w.y; acc.z += x * w.z; acc.w += x * w.w;
            }
            *(float4*)(&s_part[ks * 128 + 4 * q]) = acc;
        }
    }
    __syncthreads();
    if (tid < 128) {
        float a = gb1[tid];
        #pragma unroll
        for (int ks = 0; ks < 16; ++ks) a += s_part[ks * 128 + tid];
        s_gh[tid] = fmaxf(a, 0.f);
    }
    __syncthreads();

    // ---- P5: logits + top-2 softmax ----
    if (tid < 64) {
        float h0 = s_gh[tid], h1 = s_gh[tid + 64];
        float logit[NE];
        #pragma unroll
        for (int j = 0; j < NE; ++j) {
            float p = h0 * gW2[tid * NE + j] + h1 * gW2[(tid + 64) * NE + j];
            p = wave_reduce(p);
            logit[j] = p + gb2[j];
        }
        if (tid == 0) {
            int i1 = 0; float v1 = logit[0];
            #pragma unroll
            for (int i = 1; i < NE; ++i) if (logit[i] > v1) { v1 = logit[i]; i1 = i; }
            int i2 = -1; float v2 = -__builtin_inff();
            #pragma unroll
            for (int i = 0; i < NE; ++i) {
                if (i == i1) continue;
                if (logit[i] > v2) { v2 = logit[i]; i2 = i; }
            }
            float ex = __expf(v2 - v1);
            float inv = 1.f / (1.f + ex);
            s_isel[0] = i1; s_isel[1] = i2;
            ws[WS_SEL + b * 4 + 0] = (float)i1;
            ws[WS_SEL + b * 4 + 1] = (float)i2;
            ws[WS_SEL + b * 4 + 2] = inv;
            ws[WS_SEL + b * 4 + 3] = ex * inv;
        }
    }
    __syncthreads();

    // ---- P6: u for the 2 ACTIVE experts, 16-way K-split, float4 ----
    {
        int es = tid >> 9, ks = (tid >> 5) & 15, h4 = tid & 31;
        int e = s_isel[es];
        int i0 = ks * 20, i1 = min(i0 + 20, GLOBAL_F);
        const float* wp = eW1 + (size_t)e * EXP_IN * 128 + 4 * h4;
        float4 acc = {0.f, 0.f, 0.f, 0.f};
        #pragma unroll
        for (int i = i0; i < i1; ++i) {
            float4 w = *(const float4*)(wp + (size_t)i * 128);
            float x = s_g[i];
            acc.x += x * w.x; acc.y += x * w.y; acc.z += x * w.z; acc.w += x * w.w;
        }
        *(float4*)(&s_pu[(es * 16 + ks) * 128 + 4 * h4]) = acc;
    }
    __syncthreads();
    if (tid < 256) {
        int es = tid >> 7, h = tid & 127;
        int e = s_isel[es];
        float a = eb1[e * 128 + h];
        #pragma unroll
        for (int ks = 0; ks < 16; ++ks) a += s_pu[(es * 16 + ks) * 128 + h];
        ws[WS_U + (size_t)b * 256 + es * 128 + h] = a;
    }
}

// ---------------------------------------------------------------------------
// C: epilogue over transposed v. grid = 256 b x 4 quads, 256 thr (4 waves).
// wave -> tile (64 genes), lane -> gene: every v load is a coalesced
// 256B wave access; u/w2 are LDS broadcasts; pred writes coalesced.
// ---------------------------------------------------------------------------
__global__ __launch_bounds__(256) void c_kernel(
    const float* __restrict__ eW2, const float* __restrict__ eb2,
    const float* __restrict__ ws, float* __restrict__ pred)
{
    __shared__ float s_u[256];
    __shared__ float s_w2[256];
    const int b = blockIdx.x >> 2, quad = blockIdx.x & 3, tid = threadIdx.x;

    const int ea = (int)ws[WS_SEL + b * 4 + 0];
    const int eb = (int)ws[WS_SEL + b * 4 + 1];
    const float gA = ws[WS_SEL + b * 4 + 2];
    const float gB = ws[WS_SEL + b * 4 + 3];
    const float bA = eb2[ea], bB = eb2[eb];

    s_u[tid] = ws[WS_U + (size_t)b * 256 + tid];
    s_w2[tid] = (tid < 128) ? eW2[ea * 128 + tid] : eW2[eb * 128 + (tid - 128)];
    __syncthreads();

    const int wv = tid >> 6, lane = tid & 63;
    const int tile = quad * 4 + wv;
    const float* vA = ws + WS_V + ((size_t)tile * 512 + ea * 128) * 64 + lane;
    const float* vB = ws + WS_V + ((size_t)tile * 512 + eb * 128) * 64 + lane;

    float dA = 0.f, dB = 0.f;
    #pragma unroll 8
    for (int h = 0; h < 128; ++h) {
        dA += fmaxf(s_u[h]       + vA[(size_t)h * 64], 0.f) * s_w2[h];
        dB += fmaxf(s_u[128 + h] + vB[(size_t)h * 64], 0.f) * s_w2[128 + h];
    }
    const int g = tile * 64 + lane;
    if (g < NG) pred[(size_t)b * NG + g] = gA * (dA + bA) + gB * (dB + bB);
}

// ---------------------------------------------------------------------------
extern "C" void kernel_launch(void* const* d_in, const int* in_sizes, int n_in,
                              void* d_out, int out_size, void* d_ws, size_t ws_size,
                              hipStream_t stream) {
    const float* drug  = (const float*)d_in[0];
    const float* gex   = (const float*)d_in[1];
    const float* idose = (const float*)d_in[2];
    const float* cW1 = (const float*)d_in[3];  const float* cb1 = (const float*)d_in[4];
    const float* cW2 = (const float*)d_in[5];  const float* cb2 = (const float*)d_in[6];
    const float* cW3 = (const float*)d_in[7];  const float* cb3 = (const float*)d_in[8];
    const float* dW1 = (const float*)d_in[9];  const float* db1 = (const float*)d_in[10];
    const float* dW2 = (const float*)d_in[11]; const float* db2 = (const float*)d_in[12];
    const float* gene = (const float*)d_in[13];
    const float* gW1 = (const float*)d_in[14]; const float* gb1 = (const float*)d_in[15];
    const float* gW2 = (const float*)d_in[16]; const float* gb2 = (const float*)d_in[17];
    const float* eW1 = (const float*)d_in[18]; const float* eb1 = (const float*)d_in[19];
    const float* eW2 = (const float*)d_in[20]; const float* eb2 = (const float*)d_in[21];

    float* ws   = (float*)d_ws;
    float* out  = (float*)d_out;
    float* pred = out;               // [B, G]
    float* cell = out + NB * NG;     // [B, 50]

    ab_kernel<<<AB_GRID, 1024, 0, stream>>>(drug, gex, idose,
        cW1, cb1, cW2, cb2, cW3, cb3, dW1, db1, dW2, db2,
        gW1, gb1, gW2, gb2, eW1, eb1, gene, ws, cell);
    c_kernel<<<NB * 4, 256, 0, stream>>>(eW2, eb2, ws, pred);
}

// Round 11
// 154.291 us; speedup vs baseline: 1.1936x; 1.1670x over previous
//
#include <hip/hip_runtime.h>

#define NB 256
#define NA 64
#define NG 978
#define CELL_IN 978
#define DOSE_IN 12
#define GLOBAL_F 306
#define EXP_IN 434
#define NE 4

// ---- workspace layout (float offsets) ----
// v is stored GENE-TRANSPOSED: v_t[tile][e*128+h][64]  (16 tiles of 64 genes)
#define WS_SEL 0                       // [256][4] : e1, e2, gate1, gate2
#define WS_U   (WS_SEL + NB*4)         // [256][2][128]
#define WS_V   (WS_U + NB*256)         // [16][512][64] = 524288 floats
// total ~591k floats ~2.4 MB

#define A_BLOCKS 64                    // 16 tiles x 4 experts
#define AB_GRID  (NB + A_BLOCKS)

__device__ __forceinline__ float wave_reduce(float p) {
    #pragma unroll
    for (int off = 32; off > 0; off >>= 1) p += __shfl_down(p, off, 64);
    return p;
}

// ---------------------------------------------------------------------------
// AB: blocks [0,256): per-batch pipeline — VERBATIM r8 code (static shared
//     arrays, r8 P1). blocks [256,320): v_t producer, transposed coalesced
//     stores (r10 design, the part that worked).
// ---------------------------------------------------------------------------
__global__ __launch_bounds__(1024) void ab_kernel(
    const float* __restrict__ drug, const float* __restrict__ gex,
    const float* __restrict__ idose,
    const float* __restrict__ cW1, const float* __restrict__ cb1,
    const float* __restrict__ cW2, const float* __restrict__ cb2,
    const float* __restrict__ cW3, const float* __restrict__ cb3,
    const float* __restrict__ dW1, const float* __restrict__ db1,
    const float* __restrict__ dW2, const float* __restrict__ db2,
    const float* __restrict__ gW1, const float* __restrict__ gb1,
    const float* __restrict__ gW2, const float* __restrict__ gb2,
    const float* __restrict__ eW1, const float* __restrict__ eb1,
    const float* __restrict__ gene,
    float* __restrict__ ws, float* __restrict__ cell_out)
{
    __shared__ float s_gex[CELL_IN];
    __shared__ float s_g[GLOBAL_F];
    __shared__ float s_h1[200];
    __shared__ float s_h2[100];
    __shared__ float s_gh[128];
    __shared__ float s_d1[64];
    __shared__ int   s_isel[2];
    __shared__ float s_part[16 * 200];
    __shared__ float s_pu[32 * 128];
    __shared__ float s_gene[64 * 129];   // a-part only (padded)

    const int blk = blockIdx.x, tid = threadIdx.x;

    if (blk >= NB) {
        // ============ a-part: v_t[tile][e*128+h][g_in], coalesced ==========
        const int ablk = blk - NB;            // 0..63
        const int tile = ablk >> 2, e = ablk & 3;

        for (int i = tid; i < 64 * 128; i += 1024) {
            int gl = i >> 7, k = i & 127;
            int g = tile * 64 + gl;
            s_gene[gl * 129 + k] = (g < NG) ? gene[g * 128 + k] : 0.f;
        }
        __syncthreads();

        const int h16 = tid >> 6, g_in = tid & 63;   // 16 h-slices x 64 genes
        const float* wbase = eW1 + ((size_t)e * EXP_IN + GLOBAL_F) * 128 + h16 * 8;
        float acc[8] = {};
        #pragma unroll 4
        for (int k = 0; k < 128; ++k) {
            float x = s_gene[g_in * 129 + k];        // padded: conflict-free
            float4 w0 = *(const float4*)(wbase + (size_t)k * 128);
            float4 w1 = *(const float4*)(wbase + (size_t)k * 128 + 4);
            acc[0] += x * w0.x; acc[1] += x * w0.y;
            acc[2] += x * w0.z; acc[3] += x * w0.w;
            acc[4] += x * w1.x; acc[5] += x * w1.y;
            acc[6] += x * w1.z; acc[7] += x * w1.w;
        }
        float* vout = ws + WS_V + ((size_t)tile * 512 + e * 128 + h16 * 8) * 64 + g_in;
        #pragma unroll
        for (int j = 0; j < 8; ++j) vout[(size_t)j * 64] = acc[j];  // lane=gene: coalesced
        return;
    }

    // ==================== b-part: per-batch pipeline (r8 verbatim) =========
    const int b = blk;

    // ---- P0: stage gex; drug partials; dose layer1 ----
    if (tid < CELL_IN) s_gex[tid] = gex[b * CELL_IN + tid];
    {
        int row = tid >> 7, d = tid & 127;
        const float* p = drug + ((size_t)b * NA) * 128 + d;
        float acc = 0.f;
        #pragma unroll
        for (int i = 0; i < 8; ++i) acc += p[(size_t)(i * 8 + row) * 128];
        s_pu[row * 128 + d] = acc;
    }
    __syncthreads();
    if (tid < 128) {
        float a = 0.f;
        #pragma unroll
        for (int r = 0; r < 8; ++r) a += s_pu[r * 128 + tid];
        s_g[tid] = a;
    } else if (tid < 192) {
        int j = tid - 128;
        float acc = db1[j];
        #pragma unroll
        for (int i = 0; i < DOSE_IN; ++i)
            acc += idose[b * DOSE_IN + i] * dW1[i * 64 + j];
        s_d1[j] = fmaxf(acc, 0.f);
    }
    __syncthreads();
    if (tid < 128) {
        float acc = db2[tid];
        #pragma unroll 8
        for (int i = 0; i < 64; ++i) acc += s_d1[i] * dW2[i * 128 + tid];
        s_g[178 + tid] = fmaxf(acc, 0.f);
    }
    __syncthreads();

    // ---- P1: cell1 978->200, 16-way K-split, float4 (r8 form) ----
    {
        int q = tid & 63, ks = tid >> 6;
        if (q < 50) {
            int i0 = ks * 62, i1 = min(i0 + 62, CELL_IN);
            float4 acc = {0.f, 0.f, 0.f, 0.f};
            #pragma unroll 4
            for (int i = i0; i < i1; ++i) {
                float4 w = *(const float4*)(cW1 + (size_t)i * 200 + 4 * q);
                float x = s_gex[i];
                acc.x += x * w.x; acc.y += x * w.y; acc.z += x * w.z; acc.w += x * w.w;
            }
            *(float4*)(&s_part[ks * 200 + 4 * q]) = acc;
        }
    }
    __syncthreads();
    if (tid < 200) {
        float a = cb1[tid];
        #pragma unroll
        for (int ks = 0; ks < 16; ++ks) a += s_part[ks * 200 + tid];
        s_h1[tid] = fmaxf(a, 0.f);
    }
    __syncthreads();

    // ---- P2: cell2 200->100, 16-way K-split, float4 ----
    {
        int q = tid & 31, ks = tid >> 5;
        if (q < 25 && ks < 16) {
            int i0 = ks * 13, i1 = min(i0 + 13, 200);
            float4 acc = {0.f, 0.f, 0.f, 0.f};
            #pragma unroll
            for (int i = i0; i < i1; ++i) {
                float4 w = *(const float4*)(cW2 + (size_t)i * 100 + 4 * q);
                float x = s_h1[i];
                acc.x += x * w.x; acc.y += x * w.y; acc.z += x * w.z; acc.w += x * w.w;
            }
            *(float4*)(&s_part[ks * 100 + 4 * q]) = acc;
        }
    }
    __syncthreads();
    if (tid < 100) {
        float a = cb2[tid];
        #pragma unroll
        for (int ks = 0; ks < 16; ++ks) a += s_part[ks * 100 + tid];
        s_h2[tid] = fmaxf(a, 0.f);
    }
    __syncthreads();

    // ---- P3: cell3 100->50, 8-way K-split ----
    {
        int j = tid & 63, ks = tid >> 6;
        if (j < 50 && ks < 8) {
            int i0 = ks * 13, i1 = min(i0 + 13, 100);
            float acc = 0.f;
            #pragma unroll
            for (int i = i0; i < i1; ++i) acc += s_h2[i] * cW3[i * 50 + j];
            s_part[ks * 64 + j] = acc;
        }
    }
    __syncthreads();
    if (tid < 50) {
        float a = cb3[tid];
        #pragma unroll
        for (int ks = 0; ks < 8; ++ks) a += s_part[ks * 64 + tid];
        float r = fmaxf(a, 0.f);
        s_g[128 + tid] = r;
        cell_out[b * 50 + tid] = r;
    }
    __syncthreads();

    // ---- P4: gate1 306->128, 16-way K-split, float4 ----
    {
        int q = tid & 31, ks = tid >> 5;
        if (ks < 16) {
            int i0 = ks * 20, i1 = min(i0 + 20, GLOBAL_F);
            float4 acc = {0.f, 0.f, 0.f, 0.f};
            #pragma unroll
            for (int i = i0; i < i1; ++i) {
                float4 w = *(const float4*)(gW1 + (size_t)i * 128 + 4 * q);
                float x = s_g[i];
                acc.x += x * w.x; acc.y += x * w.y; acc.z += x * w.z; acc.w += x * w.w;
            }
            *(float4*)(&s_part[ks * 128 + 4 * q]) = acc;
        }
    }
    __syncthreads();
    if (tid < 128) {
        float a = gb1[tid];
        #pragma unroll
        for (int ks = 0; ks < 16; ++ks) a += s_part[ks * 128 + tid];
        s_gh[tid] = fmaxf(a, 0.f);
    }
    __syncthreads();

    // ---- P5: logits + top-2 softmax -> s_isel, ws sel ----
    if (tid < 64) {
        float h0 = s_gh[tid], h1 = s_gh[tid + 64];
        float logit[NE];
        #pragma unroll
        for (int j = 0; j < NE; ++j) {
            float p = h0 * gW2[tid * NE + j] + h1 * gW2[(tid + 64) * NE + j];
            p = wave_reduce(p);
            logit[j] = p + gb2[j];
        }
        if (tid == 0) {
            int i1 = 0; float v1 = logit[0];
            #pragma unroll
            for (int i = 1; i < NE; ++i) if (logit[i] > v1) { v1 = logit[i]; i1 = i; }
            int i2 = -1; float v2 = -__builtin_inff();
            #pragma unroll
            for (int i = 0; i < NE; ++i) {
                if (i == i1) continue;
                if (logit[i] > v2) { v2 = logit[i]; i2 = i; }
            }
            float ex = __expf(v2 - v1);
            float inv = 1.f / (1.f + ex);
            s_isel[0] = i1; s_isel[1] = i2;
            ws[WS_SEL + b * 4 + 0] = (float)i1;
            ws[WS_SEL + b * 4 + 1] = (float)i2;
            ws[WS_SEL + b * 4 + 2] = inv;
            ws[WS_SEL + b * 4 + 3] = ex * inv;
        }
    }
    __syncthreads();

    // ---- P6: u for the 2 ACTIVE experts, 16-way K-split, float4 ----
    {
        int es = tid >> 9, ks = (tid >> 5) & 15, h4 = tid & 31;
        int e = s_isel[es];
        int i0 = ks * 20, i1 = min(i0 + 20, GLOBAL_F);
        const float* wp = eW1 + (size_t)e * EXP_IN * 128 + 4 * h4;
        float4 acc = {0.f, 0.f, 0.f, 0.f};
        #pragma unroll
        for (int i = i0; i < i1; ++i) {
            float4 w = *(const float4*)(wp + (size_t)i * 128);
            float x = s_g[i];
            acc.x += x * w.x; acc.y += x * w.y; acc.z += x * w.z; acc.w += x * w.w;
        }
        *(float4*)(&s_pu[(es * 16 + ks) * 128 + 4 * h4]) = acc;
    }
    __syncthreads();
    if (tid < 256) {
        int es = tid >> 7, h = tid & 127;
        int e = s_isel[es];
        float a = eb1[e * 128 + h];
        #pragma unroll
        for (int ks = 0; ks < 16; ++ks) a += s_pu[(es * 16 + ks) * 128 + h];
        ws[WS_U + (size_t)b * 256 + es * 128 + h] = a;
    }
}

// ---------------------------------------------------------------------------
// C: epilogue over transposed v (r10 design — the proven win).
// grid = 256 b x 4 quads, 256 thr; wave -> 64-gene tile, lane -> gene.
// Every v load is a coalesced 256B wave access; u/w2 LDS broadcasts;
// pred writes coalesced.
// ---------------------------------------------------------------------------
__global__ __launch_bounds__(256) void c_kernel(
    const float* __restrict__ eW2, const float* __restrict__ eb2,
    const float* __restrict__ ws, float* __restrict__ pred)
{
    __shared__ float s_u[256];
    __shared__ float s_w2[256];
    const int b = blockIdx.x >> 2, quad = blockIdx.x & 3, tid = threadIdx.x;

    const int ea = (int)ws[WS_SEL + b * 4 + 0];
    const int eb = (int)ws[WS_SEL + b * 4 + 1];
    const float gA = ws[WS_SEL + b * 4 + 2];
    const float gB = ws[WS_SEL + b * 4 + 3];
    const float bA = eb2[ea], bB = eb2[eb];

    s_u[tid] = ws[WS_U + (size_t)b * 256 + tid];
    s_w2[tid] = (tid < 128) ? eW2[ea * 128 + tid] : eW2[eb * 128 + (tid - 128)];
    __syncthreads();

    const int wv = tid >> 6, lane = tid & 63;
    const int tile = quad * 4 + wv;
    const float* vA = ws + WS_V + ((size_t)tile * 512 + ea * 128) * 64 + lane;
    const float* vB = ws + WS_V + ((size_t)tile * 512 + eb * 128) * 64 + lane;

    float dA = 0.f, dB = 0.f;
    #pragma unroll 8
    for (int h = 0; h < 128; ++h) {
        dA += fmaxf(s_u[h]       + vA[(size_t)h * 64], 0.f) * s_w2[h];
        dB += fmaxf(s_u[128 + h] + vB[(size_t)h * 64], 0.f) * s_w2[128 + h];
    }
    const int g = tile * 64 + lane;
    if (g < NG) pred[(size_t)b * NG + g] = gA * (dA + bA) + gB * (dB + bB);
}

// ---------------------------------------------------------------------------
extern "C" void kernel_launch(void* const* d_in, const int* in_sizes, int n_in,
                              void* d_out, int out_size, void* d_ws, size_t ws_size,
                              hipStream_t stream) {
    const float* drug  = (const float*)d_in[0];
    const float* gex   = (const float*)d_in[1];
    const float* idose = (const float*)d_in[2];
    const float* cW1 = (const float*)d_in[3];  const float* cb1 = (const float*)d_in[4];
    const float* cW2 = (const float*)d_in[5];  const float* cb2 = (const float*)d_in[6];
    const float* cW3 = (const float*)d_in[7];  const float* cb3 = (const float*)d_in[8];
    const float* dW1 = (const float*)d_in[9];  const float* db1 = (const float*)d_in[10];
    const float* dW2 = (const float*)d_in[11]; const float* db2 = (const float*)d_in[12];
    const float* gene = (const float*)d_in[13];
    const float* gW1 = (const float*)d_in[14]; const float* gb1 = (const float*)d_in[15];
    const float* gW2 = (const float*)d_in[16]; const float* gb2 = (const float*)d_in[17];
    const float* eW1 = (const float*)d_in[18]; const float* eb1 = (const float*)d_in[19];
    const float* eW2 = (const float*)d_in[20]; const float* eb2 = (const float*)d_in[21];

    float* ws   = (float*)d_ws;
    float* out  = (float*)d_out;
    float* pred = out;               // [B, G]
    float* cell = out + NB * NG;     // [B, 50]

    ab_kernel<<<AB_GRID, 1024, 0, stream>>>(drug, gex, idose,
        cW1, cb1, cW2, cb2, cW3, cb3, dW1, db1, dW2, db2,
        gW1, gb1, gW2, gb2, eW1, eb1, gene, ws, cell);
    c_kernel<<<NB * 4, 256, 0, stream>>>(eW2, eb2, ws, pred);
}

// Round 12
// 150.054 us; speedup vs baseline: 1.2273x; 1.0282x over previous
//
#include <hip/hip_runtime.h>

#define NB 256
#define NA 64
#define NG 978
#define CELL_IN 978
#define DOSE_IN 12
#define GLOBAL_F 306
#define EXP_IN 434
#define NE 4

// ---- workspace layout (float offsets) ----
// v is stored GENE-TRANSPOSED: v_t[tile][e*128+h][64]  (16 tiles of 64 genes)
#define WS_SEL 0                       // [256][4] : e1, e2, gate1, gate2
#define WS_U   (WS_SEL + NB*4)         // [256][2][128]
#define WS_V   (WS_U + NB*256)         // [16][512][64] = 524288 floats
// total ~591k floats ~2.4 MB

#define A_BLOCKS 256                   // 16 tiles x 4 experts x 4 h-quarters
#define AB_GRID  (NB + A_BLOCKS)       // 512 blocks -> 2 blocks/CU everywhere

__device__ __forceinline__ float wave_reduce(float p) {
    #pragma unroll
    for (int off = 32; off > 0; off >>= 1) p += __shfl_down(p, off, 64);
    return p;
}

// ---------------------------------------------------------------------------
// AB: blocks [0,256): per-batch pipeline (r11 verbatim — proven 48 us).
//     blocks [256,512): v_t producer, one (64-gene tile, expert, h-quarter)
//     per block — 4x finer than r11 so every CU hosts 2 independent blocks.
// ---------------------------------------------------------------------------
__global__ __launch_bounds__(1024) void ab_kernel(
    const float* __restrict__ drug, const float* __restrict__ gex,
    const float* __restrict__ idose,
    const float* __restrict__ cW1, const float* __restrict__ cb1,
    const float* __restrict__ cW2, const float* __restrict__ cb2,
    const float* __restrict__ cW3, const float* __restrict__ cb3,
    const float* __restrict__ dW1, const float* __restrict__ db1,
    const float* __restrict__ dW2, const float* __restrict__ db2,
    const float* __restrict__ gW1, const float* __restrict__ gb1,
    const float* __restrict__ gW2, const float* __restrict__ gb2,
    const float* __restrict__ eW1, const float* __restrict__ eb1,
    const float* __restrict__ gene,
    float* __restrict__ ws, float* __restrict__ cell_out)
{
    __shared__ float s_gex[CELL_IN];
    __shared__ float s_g[GLOBAL_F];
    __shared__ float s_h1[200];
    __shared__ float s_h2[100];
    __shared__ float s_gh[128];
    __shared__ float s_d1[64];
    __shared__ int   s_isel[2];
    __shared__ float s_part[16 * 200];
    __shared__ float s_pu[32 * 128];
    __shared__ float s_gene[64 * 129];   // a-part only (padded)

    const int blk = blockIdx.x, tid = threadIdx.x;

    if (blk >= NB) {
        // ===== a-part: v_t[tile][e*128+h][g_in], (tile,e,hq) per block =====
        const int ablk = blk - NB;                 // 0..255
        const int tile = ablk >> 4, e = (ablk >> 2) & 3, hq = ablk & 3;

        for (int i = tid; i < 64 * 128; i += 1024) {
            int gl = i >> 7, k = i & 127;
            int g = tile * 64 + gl;
            s_gene[gl * 129 + k] = (g < NG) ? gene[g * 128 + k] : 0.f;
        }
        __syncthreads();

        const int slice = tid >> 6, g_in = tid & 63;   // 16 slices x 64 genes
        const int h0 = hq * 32 + slice * 2;            // 2 h-values per thread
        const float* wbase = eW1 + ((size_t)e * EXP_IN + GLOBAL_F) * 128 + h0;
        float a0 = 0.f, a1 = 0.f;
        #pragma unroll 8
        for (int k = 0; k < 128; ++k) {
            float x = s_gene[g_in * 129 + k];          // padded: conflict-free
            float2 w = *(const float2*)(wbase + (size_t)k * 128);
            a0 += x * w.x; a1 += x * w.y;
        }
        float* vout = ws + WS_V + ((size_t)tile * 512 + e * 128 + h0) * 64 + g_in;
        vout[0]  = a0;                                 // lane=gene: coalesced
        vout[64] = a1;
        return;
    }

    // ==================== b-part: per-batch pipeline (r11 verbatim) ========
    const int b = blk;

    // ---- P0: stage gex; drug partials; dose layer1 ----
    if (tid < CELL_IN) s_gex[tid] = gex[b * CELL_IN + tid];
    {
        int row = tid >> 7, d = tid & 127;
        const float* p = drug + ((size_t)b * NA) * 128 + d;
        float acc = 0.f;
        #pragma unroll
        for (int i = 0; i < 8; ++i) acc += p[(size_t)(i * 8 + row) * 128];
        s_pu[row * 128 + d] = acc;
    }
    __syncthreads();
    if (tid < 128) {
        float a = 0.f;
        #pragma unroll
        for (int r = 0; r < 8; ++r) a += s_pu[r * 128 + tid];
        s_g[tid] = a;
    } else if (tid < 192) {
        int j = tid - 128;
        float acc = db1[j];
        #pragma unroll
        for (int i = 0; i < DOSE_IN; ++i)
            acc += idose[b * DOSE_IN + i] * dW1[i * 64 + j];
        s_d1[j] = fmaxf(acc, 0.f);
    }
    __syncthreads();
    if (tid < 128) {
        float acc = db2[tid];
        #pragma unroll 8
        for (int i = 0; i < 64; ++i) acc += s_d1[i] * dW2[i * 128 + tid];
        s_g[178 + tid] = fmaxf(acc, 0.f);
    }
    __syncthreads();

    // ---- P1: cell1 978->200, 16-way K-split, float4 ----
    {
        int q = tid & 63, ks = tid >> 6;
        if (q < 50) {
            int i0 = ks * 62, i1 = min(i0 + 62, CELL_IN);
            float4 acc = {0.f, 0.f, 0.f, 0.f};
            #pragma unroll 4
            for (int i = i0; i < i1; ++i) {
                float4 w = *(const float4*)(cW1 + (size_t)i * 200 + 4 * q);
                float x = s_gex[i];
                acc.x += x * w.x; acc.y += x * w.y; acc.z += x * w.z; acc.w += x * w.w;
            }
            *(float4*)(&s_part[ks * 200 + 4 * q]) = acc;
        }
    }
    __syncthreads();
    if (tid < 200) {
        float a = cb1[tid];
        #pragma unroll
        for (int ks = 0; ks < 16; ++ks) a += s_part[ks * 200 + tid];
        s_h1[tid] = fmaxf(a, 0.f);
    }
    __syncthreads();

    // ---- P2: cell2 200->100, 16-way K-split, float4 ----
    {
        int q = tid & 31, ks = tid >> 5;
        if (q < 25 && ks < 16) {
            int i0 = ks * 13, i1 = min(i0 + 13, 200);
            float4 acc = {0.f, 0.f, 0.f, 0.f};
            #pragma unroll
            for (int i = i0; i < i1; ++i) {
                float4 w = *(const float4*)(cW2 + (size_t)i * 100 + 4 * q);
                float x = s_h1[i];
                acc.x += x * w.x; acc.y += x * w.y; acc.z += x * w.z; acc.w += x * w.w;
            }
            *(float4*)(&s_part[ks * 100 + 4 * q]) = acc;
        }
    }
    __syncthreads();
    if (tid < 100) {
        float a = cb2[tid];
        #pragma unroll
        for (int ks = 0; ks < 16; ++ks) a += s_part[ks * 100 + tid];
        s_h2[tid] = fmaxf(a, 0.f);
    }
    __syncthreads();

    // ---- P3: cell3 100->50, 8-way K-split ----
    {
        int j = tid & 63, ks = tid >> 6;
        if (j < 50 && ks < 8) {
            int i0 = ks * 13, i1 = min(i0 + 13, 100);
            float acc = 0.f;
            #pragma unroll
            for (int i = i0; i < i1; ++i) acc += s_h2[i] * cW3[i * 50 + j];
            s_part[ks * 64 + j] = acc;
        }
    }
    __syncthreads();
    if (tid < 50) {
        float a = cb3[tid];
        #pragma unroll
        for (int ks = 0; ks < 8; ++ks) a += s_part[ks * 64 + tid];
        float r = fmaxf(a, 0.f);
        s_g[128 + tid] = r;
        cell_out[b * 50 + tid] = r;
    }
    __syncthreads();

    // ---- P4: gate1 306->128, 16-way K-split, float4 ----
    {
        int q = tid & 31, ks = tid >> 5;
        if (ks < 16) {
            int i0 = ks * 20, i1 = min(i0 + 20, GLOBAL_F);
            float4 acc = {0.f, 0.f, 0.f, 0.f};
            #pragma unroll
            for (int i = i0; i < i1; ++i) {
                float4 w = *(const float4*)(gW1 + (size_t)i * 128 + 4 * q);
                float x = s_g[i];
                acc.x += x * w.x; acc.y += x * w.y; acc.z += x * w.z; acc.w += x * w.w;
            }
            *(float4*)(&s_part[ks * 128 + 4 * q]) = acc;
        }
    }
    __syncthreads();
    if (tid < 128) {
        float a = gb1[tid];
        #pragma unroll
        for (int ks = 0; ks < 16; ++ks) a += s_part[ks * 128 + tid];
        s_gh[tid] = fmaxf(a, 0.f);
    }
    __syncthreads();

    // ---- P5: logits + top-2 softmax -> s_isel, ws sel ----
    if (tid < 64) {
        float h0 = s_gh[tid], h1 = s_gh[tid + 64];
        float logit[NE];
        #pragma unroll
        for (int j = 0; j < NE; ++j) {
            float p = h0 * gW2[tid * NE + j] + h1 * gW2[(tid + 64) * NE + j];
            p = wave_reduce(p);
            logit[j] = p + gb2[j];
        }
        if (tid == 0) {
            int i1 = 0; float v1 = logit[0];
            #pragma unroll
            for (int i = 1; i < NE; ++i) if (logit[i] > v1) { v1 = logit[i]; i1 = i; }
            int i2 = -1; float v2 = -__builtin_inff();
            #pragma unroll
            for (int i = 0; i < NE; ++i) {
                if (i == i1) continue;
                if (logit[i] > v2) { v2 = logit[i]; i2 = i; }
            }
            float ex = __expf(v2 - v1);
            float inv = 1.f / (1.f + ex);
            s_isel[0] = i1; s_isel[1] = i2;
            ws[WS_SEL + b * 4 + 0] = (float)i1;
            ws[WS_SEL + b * 4 + 1] = (float)i2;
            ws[WS_SEL + b * 4 + 2] = inv;
            ws[WS_SEL + b * 4 + 3] = ex * inv;
        }
    }
    __syncthreads();

    // ---- P6: u for the 2 ACTIVE experts, 16-way K-split, float4 ----
    {
        int es = tid >> 9, ks = (tid >> 5) & 15, h4 = tid & 31;
        int e = s_isel[es];
        int i0 = ks * 20, i1 = min(i0 + 20, GLOBAL_F);
        const float* wp = eW1 + (size_t)e * EXP_IN * 128 + 4 * h4;
        float4 acc = {0.f, 0.f, 0.f, 0.f};
        #pragma unroll
        for (int i = i0; i < i1; ++i) {
            float4 w = *(const float4*)(wp + (size_t)i * 128);
            float x = s_g[i];
            acc.x += x * w.x; acc.y += x * w.y; acc.z += x * w.z; acc.w += x * w.w;
        }
        *(float4*)(&s_pu[(es * 16 + ks) * 128 + 4 * h4]) = acc;
    }
    __syncthreads();
    if (tid < 256) {
        int es = tid >> 7, h = tid & 127;
        int e = s_isel[es];
        float a = eb1[e * 128 + h];
        #pragma unroll
        for (int ks = 0; ks < 16; ++ks) a += s_pu[(es * 16 + ks) * 128 + h];
        ws[WS_U + (size_t)b * 256 + es * 128 + h] = a;
    }
}

// ---------------------------------------------------------------------------
// C: epilogue over transposed v (r10/r11 design — proven).
// grid = 256 b x 4 quads, 256 thr; wave -> 64-gene tile, lane -> gene.
// ---------------------------------------------------------------------------
__global__ __launch_bounds__(256) void c_kernel(
    const float* __restrict__ eW2, const float* __restrict__ eb2,
    const float* __restrict__ ws, float* __restrict__ pred)
{
    __shared__ float s_u[256];
    __shared__ float s_w2[256];
    const int b = blockIdx.x >> 2, quad = blockIdx.x & 3, tid = threadIdx.x;

    const int ea = (int)ws[WS_SEL + b * 4 + 0];
    const int eb = (int)ws[WS_SEL + b * 4 + 1];
    const float gA = ws[WS_SEL + b * 4 + 2];
    const float gB = ws[WS_SEL + b * 4 + 3];
    const float bA = eb2[ea], bB = eb2[eb];

    s_u[tid] = ws[WS_U + (size_t)b * 256 + tid];
    s_w2[tid] = (tid < 128) ? eW2[ea * 128 + tid] : eW2[eb * 128 + (tid - 128)];
    __syncthreads();

    const int wv = tid >> 6, lane = tid & 63;
    const int tile = quad * 4 + wv;
    const float* vA = ws + WS_V + ((size_t)tile * 512 + ea * 128) * 64 + lane;
    const float* vB = ws + WS_V + ((size_t)tile * 512 + eb * 128) * 64 + lane;

    float dA = 0.f, dB = 0.f;
    #pragma unroll 8
    for (int h = 0; h < 128; ++h) {
        dA += fmaxf(s_u[h]       + vA[(size_t)h * 64], 0.f) * s_w2[h];
        dB += fmaxf(s_u[128 + h] + vB[(size_t)h * 64], 0.f) * s_w2[128 + h];
    }
    const int g = tile * 64 + lane;
    if (g < NG) pred[(size_t)b * NG + g] = gA * (dA + bA) + gB * (dB + bB);
}

// ---------------------------------------------------------------------------
extern "C" void kernel_launch(void* const* d_in, const int* in_sizes, int n_in,
                              void* d_out, int out_size, void* d_ws, size_t ws_size,
                              hipStream_t stream) {
    const float* drug  = (const float*)d_in[0];
    const float* gex   = (const float*)d_in[1];
    const float* idose = (const float*)d_in[2];
    const float* cW1 = (const float*)d_in[3];  const float* cb1 = (const float*)d_in[4];
    const float* cW2 = (const float*)d_in[5];  const float* cb2 = (const float*)d_in[6];
    const float* cW3 = (const float*)d_in[7];  const float* cb3 = (const float*)d_in[8];
    const float* dW1 = (const float*)d_in[9];  const float* db1 = (const float*)d_in[10];
    const float* dW2 = (const float*)d_in[11]; const float* db2 = (const float*)d_in[12];
    const float* gene = (const float*)d_in[13];
    const float* gW1 = (const float*)d_in[14]; const float* gb1 = (const float*)d_in[15];
    const float* gW2 = (const float*)d_in[16]; const float* gb2 = (const float*)d_in[17];
    const float* eW1 = (const float*)d_in[18]; const float* eb1 = (const float*)d_in[19];
    const float* eW2 = (const float*)d_in[20]; const float* eb2 = (const float*)d_in[21];

    float* ws   = (float*)d_ws;
    float* out  = (float*)d_out;
    float* pred = out;               // [B, G]
    float* cell = out + NB * NG;     // [B, 50]

    ab_kernel<<<AB_GRID, 1024, 0, stream>>>(drug, gex, idose,
        cW1, cb1, cW2, cb2, cW3, cb3, dW1, db1, dW2, db2,
        gW1, gb1, gW2, gb2, eW1, eb1, gene, ws, cell);
    c_kernel<<<NB * 4, 256, 0, stream>>>(eW2, eb2, ws, pred);
}